// Round 1
// baseline (142.196 us; speedup 1.0000x reference)
//
#include <hip/hip_runtime.h>
#include <cmath>

// Caps2dMatwo fused forward: conv3x3 -> pos/app 4x4 transforms -> 3-round routing.
// N=2, T0=4, T1=8, H=W=128, Z=32 (16 pos + 16 app), PD=AD=4.
// One block = 4h x 8w pixel tile; 32 lanes per pixel (lane = t*4 + c).

#define TH 4
#define TW 8
#define XR (TH + 2)   // 6 rows incl. halo
#define XC (TW + 2)   // 10 cols incl. halo
#define ZPAD 36       // 32 z + 4 pad: keeps 16B alignment, breaks bank aliasing

__global__ __launch_bounds__(256, 3)
void caps_fused(const float* __restrict__ x,    // (2,4,32,128,128)
                const float* __restrict__ Wc,   // (4,3,3,1,8)
                const float* __restrict__ Wp,   // (4,16,8) -> flat [c][128]
                const float* __restrict__ Wa,   // (4,16,8) -> flat [c][128]
                const float* __restrict__ ba,   // (4,8)
                float* __restrict__ out)        // (2,8,32,128,128)
{
    __shared__ float xs[XR][XC][4][ZPAD];   // 6*10*4*36*4 = 34560 B

    const int tid = threadIdx.x;
    const int n  = blockIdx.z;
    const int h0 = blockIdx.y * TH;
    const int w0 = blockIdx.x * TW;

    // ---------- stage x halo tile into LDS (col fastest -> coalesced runs) ----------
    for (int e = tid; e < 128 * XR * XC; e += 256) {
        int col = e % XC;
        int tmp = e / XC;
        int row = tmp % XR;
        int cz  = tmp / XR;              // c*32+z, 0..127
        int gh = h0 - 1 + row;
        int gw = w0 - 1 + col;
        float v = 0.0f;
        if ((unsigned)gh < 128u && (unsigned)gw < 128u)
            v = x[(((size_t)(n * 128 + cz)) << 14) + (gh << 7) + gw];
        xs[row][col][cz >> 5][cz & 31] = v;
    }

    const int p    = tid >> 5;          // pixel column within tile
    const int lane = tid & 31;
    const int c    = lane & 3;          // t0 index
    const int t    = lane >> 2;         // output t1 index
    const int chp  = t >> 1;            // conv channel feeding pos part
    const int zoff = (t & 1) << 4;      // z-slice base (0 or 16)

    // ---------- per-thread weights (tiny, cache-hot) ----------
    float wp9[9], wa9[9];
#pragma unroll
    for (int i = 0; i < 9; ++i) {
        wp9[i] = Wc[(c * 9 + i) * 8 + chp];
        wa9[i] = Wc[(c * 9 + i) * 8 + 4 + chp];
    }
    float Mp[16], Ma[16];
#pragma unroll
    for (int q = 0; q < 16; ++q) {
        Mp[q] = Wp[c * 128 + t * 16 + q];   // [j*4+k]
        Ma[q] = Wa[c * 128 + t * 16 + q];
    }
    // column-normalize Mp (sum over j for each column k)
#pragma unroll
    for (int k = 0; k < 4; ++k) {
        float s = Mp[k] * Mp[k] + Mp[4 + k] * Mp[4 + k]
                + Mp[8 + k] * Mp[8 + k] + Mp[12 + k] * Mp[12 + k];
        float inv = 1.0f / sqrtf(fmaxf(s, 1e-12f));
        Mp[k] *= inv; Mp[4 + k] *= inv; Mp[8 + k] *= inv; Mp[12 + k] *= inv;
    }
    const float bap = ba[c * 8 + t];
    const float wx  = (float)(w0 + p) * (1.0f / 128.0f);

    __syncthreads();

    for (int g = 0; g < TH; ++g) {
        // ---------- conv 3x3: 16 z outputs for each of the two channels ----------
        float up[16], ua[16];
#pragma unroll
        for (int q = 0; q < 16; ++q) { up[q] = 0.0f; ua[q] = 0.0f; }
#pragma unroll
        for (int dy = 0; dy < 3; ++dy) {
#pragma unroll
            for (int dx = 0; dx < 3; ++dx) {
                const float* bp = &xs[g + dy][p + dx][c][zoff];
                float xv[16];
                *(float4*)&xv[0]  = *(const float4*)(bp);
                *(float4*)&xv[4]  = *(const float4*)(bp + 4);
                *(float4*)&xv[8]  = *(const float4*)(bp + 8);
                *(float4*)&xv[12] = *(const float4*)(bp + 12);
                const float w1 = wp9[dy * 3 + dx];
                const float w2 = wa9[dy * 3 + dx];
#pragma unroll
                for (int q = 0; q < 16; ++q) {
                    up[q] += xv[q] * w1;
                    ua[q] += xv[q] * w2;
                }
            }
        }

        // ---------- 4x4 transforms -> u_hat[32] ----------
        const float hy = (float)(h0 + g) * (1.0f / 128.0f);
        float uh[32];
#pragma unroll
        for (int i = 0; i < 4; ++i) {
#pragma unroll
            for (int k = 0; k < 4; ++k) {
                uh[i * 4 + k] = up[i * 4 + 0] * Mp[k]
                              + up[i * 4 + 1] * Mp[4 + k]
                              + up[i * 4 + 2] * Mp[8 + k]
                              + up[i * 4 + 3] * Mp[12 + k];
            }
            uh[i * 4 + 0] += up[i * 4 + 3] * wx;   // coord col 0 += w/W
            uh[i * 4 + 1] += up[i * 4 + 3] * hy;   // coord col 1 += h/H
        }
#pragma unroll
        for (int i = 0; i < 4; ++i) {
            const float a0 = ua[i * 4 + 0] + bap;
            const float a1 = ua[i * 4 + 1] + bap;
            const float a2 = ua[i * 4 + 2] + bap;
            const float a3 = ua[i * 4 + 3] + bap;
#pragma unroll
            for (int k = 0; k < 4; ++k)
                uh[16 + i * 4 + k] = a0 * Ma[k] + a1 * Ma[4 + k]
                                   + a2 * Ma[8 + k] + a3 * Ma[12 + k];
        }

        // ---------- routing (3 iterations, last one writes out) ----------
        float bacc = 0.0f;
#pragma unroll
        for (int it = 0; it < 3; ++it) {
            const float r = 1.0f / (1.0f + expf(-bacc));
            float pz[32];
#pragma unroll
            for (int zz = 0; zz < 32; ++zz) {
                float v = uh[zz] * r;
                v += __shfl_xor(v, 1, 64);   // reduce over c (lanes differ in bits 0-1)
                v += __shfl_xor(v, 2, 64);
                pz[zz] = v;
            }
            float mx = 0.0f;
#pragma unroll
            for (int zz = 0; zz < 16; ++zz) mx = fmaxf(mx, fabsf(pz[zz]));
            const float invm = 1.0f / mx;
            float sq = 0.0f;
#pragma unroll
            for (int zz = 16; zz < 32; ++zz) sq += pz[zz] * pz[zz];
            const float fac = sq / ((1.0f + sq) * sqrtf(sq + 1e-9f));

            if (it < 2) {
                float dp = 0.0f, da = 0.0f;
#pragma unroll
                for (int zz = 0; zz < 16; ++zz) dp += uh[zz] * pz[zz];
#pragma unroll
                for (int zz = 16; zz < 32; ++zz) da += uh[zz] * pz[zz];
                bacc += (dp * invm) * (da * fac);
            } else if (c == 0) {
                const int row = h0 + g;
                float* ob = out + (((size_t)((n * 8 + t) * 32)) << 14)
                                + (row << 7) + (w0 + p);
#pragma unroll
                for (int zz = 0; zz < 16; ++zz)
                    ob[((size_t)zz) << 14] = pz[zz] * invm;
#pragma unroll
                for (int zz = 16; zz < 32; ++zz)
                    ob[((size_t)zz) << 14] = pz[zz] * fac;
            }
        }
    }
}

extern "C" void kernel_launch(void* const* d_in, const int* in_sizes, int n_in,
                              void* d_out, int out_size, void* d_ws, size_t ws_size,
                              hipStream_t stream) {
    const float* x  = (const float*)d_in[0];
    const float* Wc = (const float*)d_in[1];
    const float* Wp = (const float*)d_in[2];
    const float* Wa = (const float*)d_in[3];
    const float* ba = (const float*)d_in[4];
    float* out = (float*)d_out;

    dim3 grid(128 / TW, 128 / TH, 2);   // (16, 32, 2)
    caps_fused<<<grid, 256, 0, stream>>>(x, Wc, Wp, Wa, ba, out);
}

// Round 2
// 139.395 us; speedup vs baseline: 1.0201x; 1.0201x over previous
//
#include <hip/hip_runtime.h>
#include <cmath>

// Caps2dMatwo fused forward: conv3x3 -> pos/app 4x4 transforms -> 3-round routing.
// N=2, T0=4, T1=8, H=W=128, Z=32 (16 pos + 16 app), PD=AD=4.
// One block = 2h x 8w pixel tile; 32 lanes per pixel (lane = t*4 + c).
// c-reduction done with DPP quad_perm adds (VALU), not LDS shuffles.
// LDS tile z-quads XOR-swizzled by (row*XC+col)&7 to kill staging bank conflicts.

#define TH 2
#define TW 8
#define XR (TH + 2)   // 4 rows incl. halo
#define XC (TW + 2)   // 10 cols incl. halo
#define ZPAD 36       // 32 z + 4 pad; stride 144B keeps 16B alignment, c-stride 4 banks

__device__ __forceinline__ float qsum4(float v) {
    // sum over the 4 lanes of each quad (lane bits 0-1 = c index)
    int a = __builtin_amdgcn_mov_dpp(__float_as_int(v), 0xB1, 0xF, 0xF, true); // quad_perm [1,0,3,2]
    v += __int_as_float(a);
    int b = __builtin_amdgcn_mov_dpp(__float_as_int(v), 0x4E, 0xF, 0xF, true); // quad_perm [2,3,0,1]
    v += __int_as_float(b);
    return v;
}

__global__ __launch_bounds__(256, 4)
void caps_fused(const float* __restrict__ x,    // (2,4,32,128,128)
                const float* __restrict__ Wc,   // (4,3,3,1,8)
                const float* __restrict__ Wp,   // (4,16,8) -> flat [c][128]
                const float* __restrict__ Wa,   // (4,16,8) -> flat [c][128]
                const float* __restrict__ ba,   // (4,8)
                float* __restrict__ out)        // (2,8,32,128,128)
{
    __shared__ float xs[XR][XC][4][ZPAD];   // 4*10*4*36*4 = 23040 B

    const int tid = threadIdx.x;
    const int n  = blockIdx.z;
    const int h0 = blockIdx.y * TH;
    const int w0 = blockIdx.x * TW;

    // ---------- stage x halo tile into LDS ----------
    // z-quad swizzle: quad' = quad ^ ((row*XC+col)&7). Spreads the per-cz
    // write (60 lanes, row-stride == 0 mod 32 banks) over ~16 banks.
    for (int e = tid; e < 128 * XR * XC; e += 256) {    // 20 iters exactly
        int col = e % XC;
        int tmp = e / XC;
        int row = tmp % XR;
        int cz  = tmp / XR;              // c*32+z, 0..127
        int gh = h0 - 1 + row;
        int gw = w0 - 1 + col;
        float v = 0.0f;
        if ((unsigned)gh < 128u && (unsigned)gw < 128u)
            v = x[(((size_t)(n * 128 + cz)) << 14) + (gh << 7) + gw];
        int z = cz & 31;
        int s = (row * XC + col) & 7;
        xs[row][col][cz >> 5][((((z >> 2) & 7) ^ s) << 2) | (z & 3)] = v;
    }

    const int p    = tid >> 5;          // pixel column within tile
    const int lane = tid & 31;
    const int c    = lane & 3;          // t0 index
    const int t    = lane >> 2;         // output t1 index
    const int chp  = t >> 1;            // conv channel feeding pos part
    const int q0   = (t & 1) << 2;      // z-quad base (0 or 4)

    // ---------- per-thread weights (tiny, cache-hot) ----------
    float wp9[9], wa9[9];
#pragma unroll
    for (int i = 0; i < 9; ++i) {
        wp9[i] = Wc[(c * 9 + i) * 8 + chp];
        wa9[i] = Wc[(c * 9 + i) * 8 + 4 + chp];
    }
    float Mp[16], Ma[16];
#pragma unroll
    for (int q = 0; q < 16; ++q) {
        Mp[q] = Wp[c * 128 + t * 16 + q];   // [j*4+k]
        Ma[q] = Wa[c * 128 + t * 16 + q];
    }
    // column-normalize Mp (sum over j for each column k)
#pragma unroll
    for (int k = 0; k < 4; ++k) {
        float s = Mp[k] * Mp[k] + Mp[4 + k] * Mp[4 + k]
                + Mp[8 + k] * Mp[8 + k] + Mp[12 + k] * Mp[12 + k];
        float inv = 1.0f / sqrtf(fmaxf(s, 1e-12f));
        Mp[k] *= inv; Mp[4 + k] *= inv; Mp[8 + k] *= inv; Mp[12 + k] *= inv;
    }
    const float bap = ba[c * 8 + t];
    const float wx  = (float)(w0 + p) * (1.0f / 128.0f);

    __syncthreads();

    for (int g = 0; g < TH; ++g) {
        // ---------- conv 3x3: 16 z outputs for each of the two channels ----------
        float up[16], ua[16];
#pragma unroll
        for (int q = 0; q < 16; ++q) { up[q] = 0.0f; ua[q] = 0.0f; }
#pragma unroll
        for (int dy = 0; dy < 3; ++dy) {
#pragma unroll
            for (int dx = 0; dx < 3; ++dx) {
                const int rr = g + dy, cc = p + dx;
                const int s = (rr * XC + cc) & 7;
                const float* bp = &xs[rr][cc][c][0];
                float xv[16];
                *(float4*)&xv[0]  = *(const float4*)(bp + (((q0 | 0) ^ s) << 2));
                *(float4*)&xv[4]  = *(const float4*)(bp + (((q0 | 1) ^ s) << 2));
                *(float4*)&xv[8]  = *(const float4*)(bp + (((q0 | 2) ^ s) << 2));
                *(float4*)&xv[12] = *(const float4*)(bp + (((q0 | 3) ^ s) << 2));
                const float w1 = wp9[dy * 3 + dx];
                const float w2 = wa9[dy * 3 + dx];
#pragma unroll
                for (int q = 0; q < 16; ++q) {
                    up[q] += xv[q] * w1;
                    ua[q] += xv[q] * w2;
                }
            }
        }

        // ---------- 4x4 transforms -> u_hat[32] ----------
        const float hy = (float)(h0 + g) * (1.0f / 128.0f);
        float uh[32];
#pragma unroll
        for (int i = 0; i < 4; ++i) {
#pragma unroll
            for (int k = 0; k < 4; ++k) {
                uh[i * 4 + k] = up[i * 4 + 0] * Mp[k]
                              + up[i * 4 + 1] * Mp[4 + k]
                              + up[i * 4 + 2] * Mp[8 + k]
                              + up[i * 4 + 3] * Mp[12 + k];
            }
            uh[i * 4 + 0] += up[i * 4 + 3] * wx;   // coord col 0 += w/W
            uh[i * 4 + 1] += up[i * 4 + 3] * hy;   // coord col 1 += h/H
        }
#pragma unroll
        for (int i = 0; i < 4; ++i) {
            const float a0 = ua[i * 4 + 0] + bap;
            const float a1 = ua[i * 4 + 1] + bap;
            const float a2 = ua[i * 4 + 2] + bap;
            const float a3 = ua[i * 4 + 3] + bap;
#pragma unroll
            for (int k = 0; k < 4; ++k)
                uh[16 + i * 4 + k] = a0 * Ma[k] + a1 * Ma[4 + k]
                                   + a2 * Ma[8 + k] + a3 * Ma[12 + k];
        }

        // ---------- routing (3 iterations, last one writes out) ----------
        float bacc = 0.0f;
#pragma unroll
        for (int it = 0; it < 3; ++it) {
            const float r = 1.0f / (1.0f + __expf(-bacc));
            float pz[32];
#pragma unroll
            for (int zz = 0; zz < 32; ++zz)
                pz[zz] = qsum4(uh[zz] * r);        // reduce over c via DPP (VALU)

            float mx = 0.0f;
#pragma unroll
            for (int zz = 0; zz < 16; ++zz) mx = fmaxf(mx, fabsf(pz[zz]));
            const float invm = 1.0f / mx;
            float sq = 0.0f;
#pragma unroll
            for (int zz = 16; zz < 32; ++zz) sq += pz[zz] * pz[zz];
            const float fac = sq / ((1.0f + sq) * sqrtf(sq + 1e-9f));

            if (it < 2) {
                float dp = 0.0f, da = 0.0f;
#pragma unroll
                for (int zz = 0; zz < 16; ++zz) dp += uh[zz] * pz[zz];
#pragma unroll
                for (int zz = 16; zz < 32; ++zz) da += uh[zz] * pz[zz];
                bacc += (dp * invm) * (da * fac);
            } else if (c == 0) {
                const int row = h0 + g;
                float* ob = out + (((size_t)((n * 8 + t) * 32)) << 14)
                                + (row << 7) + (w0 + p);
#pragma unroll
                for (int zz = 0; zz < 16; ++zz)
                    ob[((size_t)zz) << 14] = pz[zz] * invm;
#pragma unroll
                for (int zz = 16; zz < 32; ++zz)
                    ob[((size_t)zz) << 14] = pz[zz] * fac;
            }
        }
    }
}

extern "C" void kernel_launch(void* const* d_in, const int* in_sizes, int n_in,
                              void* d_out, int out_size, void* d_ws, size_t ws_size,
                              hipStream_t stream) {
    const float* x  = (const float*)d_in[0];
    const float* Wc = (const float*)d_in[1];
    const float* Wp = (const float*)d_in[2];
    const float* Wa = (const float*)d_in[3];
    const float* ba = (const float*)d_in[4];
    float* out = (float*)d_out;

    dim3 grid(128 / TW, 128 / TH, 2);   // (16, 64, 2)
    caps_fused<<<grid, 256, 0, stream>>>(x, Wc, Wp, Wa, ba, out);
}

// Round 3
// 128.626 us; speedup vs baseline: 1.1055x; 1.0837x over previous
//
#include <hip/hip_runtime.h>
#include <cmath>

// Caps2dMatwo fused forward: conv3x3 -> pos/app 4x4 transforms -> 3-round routing.
// N=2, T0=4, T1=8, H=W=128, Z=32 (16 pos + 16 app), PD=AD=4.
// One block = 2h x 8w pixel tile; 32 lanes per pixel (lane = t*4 + c).
// R3: launch_bounds(256,3) to stop register spilling (64 VGPR was forcing
// AGPR/scratch shuttling); HW rcp/rsq instead of refined divide/sqrt.

#define TH 2
#define TW 8
#define XR (TH + 2)   // 4 rows incl. halo
#define XC (TW + 2)   // 10 cols incl. halo
#define ZPAD 36       // 32 z + 4 pad; stride 144B keeps 16B alignment

__device__ __forceinline__ float qsum4(float v) {
    // sum over the 4 lanes of each quad (lane bits 0-1 = c index)
    int a = __builtin_amdgcn_mov_dpp(__float_as_int(v), 0xB1, 0xF, 0xF, true); // quad_perm [1,0,3,2]
    v += __int_as_float(a);
    int b = __builtin_amdgcn_mov_dpp(__float_as_int(v), 0x4E, 0xF, 0xF, true); // quad_perm [2,3,0,1]
    v += __int_as_float(b);
    return v;
}

__global__ __launch_bounds__(256, 3)
void caps_fused(const float* __restrict__ x,    // (2,4,32,128,128)
                const float* __restrict__ Wc,   // (4,3,3,1,8)
                const float* __restrict__ Wp,   // (4,16,8) -> flat [c][128]
                const float* __restrict__ Wa,   // (4,16,8) -> flat [c][128]
                const float* __restrict__ ba,   // (4,8)
                float* __restrict__ out)        // (2,8,32,128,128)
{
    __shared__ float xs[XR][XC][4][ZPAD];   // 4*10*4*36*4 = 23040 B

    const int tid = threadIdx.x;
    const int n  = blockIdx.z;
    const int h0 = blockIdx.y * TH;
    const int w0 = blockIdx.x * TW;

    // ---------- stage x halo tile into LDS ----------
    // z-quad swizzle: quad' = quad ^ ((row*XC+col)&7) spreads per-cz writes
    // across banks (row/col strides are 0 mod 32 banks otherwise).
    for (int e = tid; e < 128 * XR * XC; e += 256) {    // 20 iters exactly
        int col = e % XC;
        int tmp = e / XC;
        int row = tmp % XR;
        int cz  = tmp / XR;              // c*32+z, 0..127
        int gh = h0 - 1 + row;
        int gw = w0 - 1 + col;
        float v = 0.0f;
        if ((unsigned)gh < 128u && (unsigned)gw < 128u)
            v = x[(((size_t)(n * 128 + cz)) << 14) + (gh << 7) + gw];
        int z = cz & 31;
        int s = (row * XC + col) & 7;
        xs[row][col][cz >> 5][((((z >> 2) & 7) ^ s) << 2) | (z & 3)] = v;
    }

    const int p    = tid >> 5;          // pixel column within tile
    const int lane = tid & 31;
    const int c    = lane & 3;          // t0 index
    const int t    = lane >> 2;         // output t1 index
    const int chp  = t >> 1;            // conv channel feeding pos part
    const int q0   = (t & 1) << 2;      // z-quad base (0 or 4)

    // ---------- per-thread weights (tiny, cache-hot) ----------
    float wp9[9], wa9[9];
#pragma unroll
    for (int i = 0; i < 9; ++i) {
        wp9[i] = Wc[(c * 9 + i) * 8 + chp];
        wa9[i] = Wc[(c * 9 + i) * 8 + 4 + chp];
    }
    float Mp[16], Ma[16];
#pragma unroll
    for (int q = 0; q < 16; ++q) {
        Mp[q] = Wp[c * 128 + t * 16 + q];   // [j*4+k]
        Ma[q] = Wa[c * 128 + t * 16 + q];
    }
    // column-normalize Mp (sum over j for each column k)
#pragma unroll
    for (int k = 0; k < 4; ++k) {
        float s = Mp[k] * Mp[k] + Mp[4 + k] * Mp[4 + k]
                + Mp[8 + k] * Mp[8 + k] + Mp[12 + k] * Mp[12 + k];
        float inv = __builtin_amdgcn_rsqf(fmaxf(s, 1e-12f));
        Mp[k] *= inv; Mp[4 + k] *= inv; Mp[8 + k] *= inv; Mp[12 + k] *= inv;
    }
    const float bap = ba[c * 8 + t];
    const float wx  = (float)(w0 + p) * (1.0f / 128.0f);

    __syncthreads();

    for (int g = 0; g < TH; ++g) {
        // ---------- conv 3x3: 16 z outputs for each of the two channels ----------
        float up[16], ua[16];
#pragma unroll
        for (int q = 0; q < 16; ++q) { up[q] = 0.0f; ua[q] = 0.0f; }
#pragma unroll
        for (int dy = 0; dy < 3; ++dy) {
#pragma unroll
            for (int dx = 0; dx < 3; ++dx) {
                const int rr = g + dy, cc = p + dx;
                const int s = (rr * XC + cc) & 7;
                const float* bp = &xs[rr][cc][c][0];
                float xv[16];
                *(float4*)&xv[0]  = *(const float4*)(bp + (((q0 | 0) ^ s) << 2));
                *(float4*)&xv[4]  = *(const float4*)(bp + (((q0 | 1) ^ s) << 2));
                *(float4*)&xv[8]  = *(const float4*)(bp + (((q0 | 2) ^ s) << 2));
                *(float4*)&xv[12] = *(const float4*)(bp + (((q0 | 3) ^ s) << 2));
                const float w1 = wp9[dy * 3 + dx];
                const float w2 = wa9[dy * 3 + dx];
#pragma unroll
                for (int q = 0; q < 16; ++q) {
                    up[q] += xv[q] * w1;
                    ua[q] += xv[q] * w2;
                }
            }
        }

        // ---------- 4x4 transforms -> u_hat[32] ----------
        const float hy = (float)(h0 + g) * (1.0f / 128.0f);
        float uh[32];
#pragma unroll
        for (int i = 0; i < 4; ++i) {
#pragma unroll
            for (int k = 0; k < 4; ++k) {
                uh[i * 4 + k] = up[i * 4 + 0] * Mp[k]
                              + up[i * 4 + 1] * Mp[4 + k]
                              + up[i * 4 + 2] * Mp[8 + k]
                              + up[i * 4 + 3] * Mp[12 + k];
            }
            uh[i * 4 + 0] += up[i * 4 + 3] * wx;   // coord col 0 += w/W
            uh[i * 4 + 1] += up[i * 4 + 3] * hy;   // coord col 1 += h/H
        }
#pragma unroll
        for (int i = 0; i < 4; ++i) {
            const float a0 = ua[i * 4 + 0] + bap;
            const float a1 = ua[i * 4 + 1] + bap;
            const float a2 = ua[i * 4 + 2] + bap;
            const float a3 = ua[i * 4 + 3] + bap;
#pragma unroll
            for (int k = 0; k < 4; ++k)
                uh[16 + i * 4 + k] = a0 * Ma[k] + a1 * Ma[4 + k]
                                   + a2 * Ma[8 + k] + a3 * Ma[12 + k];
        }

        // ---------- routing (3 iterations, last one writes out) ----------
        float bacc = 0.0f;
#pragma unroll
        for (int it = 0; it < 3; ++it) {
            const float r = __builtin_amdgcn_rcpf(1.0f + __expf(-bacc));
            float pz[32];
#pragma unroll
            for (int zz = 0; zz < 32; ++zz)
                pz[zz] = qsum4(uh[zz] * r);        // reduce over c via DPP (VALU)

            float mx = 0.0f;
#pragma unroll
            for (int zz = 0; zz < 16; ++zz) mx = fmaxf(mx, fabsf(pz[zz]));
            const float invm = __builtin_amdgcn_rcpf(mx);
            float sq = 0.0f;
#pragma unroll
            for (int zz = 16; zz < 32; ++zz) sq += pz[zz] * pz[zz];
            // fac = sq/(1+sq) / sqrt(sq+1e-9)
            const float fac = sq * __builtin_amdgcn_rcpf(1.0f + sq)
                                 * __builtin_amdgcn_rsqf(sq + 1e-9f);

            if (it < 2) {
                float dp = 0.0f, da = 0.0f;
#pragma unroll
                for (int zz = 0; zz < 16; ++zz) dp += uh[zz] * pz[zz];
#pragma unroll
                for (int zz = 16; zz < 32; ++zz) da += uh[zz] * pz[zz];
                bacc += (dp * invm) * (da * fac);
            } else if (c == 0) {
                const int row = h0 + g;
                float* ob = out + (((size_t)((n * 8 + t) * 32)) << 14)
                                + (row << 7) + (w0 + p);
#pragma unroll
                for (int zz = 0; zz < 16; ++zz)
                    ob[((size_t)zz) << 14] = pz[zz] * invm;
#pragma unroll
                for (int zz = 16; zz < 32; ++zz)
                    ob[((size_t)zz) << 14] = pz[zz] * fac;
            }
        }
    }
}

extern "C" void kernel_launch(void* const* d_in, const int* in_sizes, int n_in,
                              void* d_out, int out_size, void* d_ws, size_t ws_size,
                              hipStream_t stream) {
    const float* x  = (const float*)d_in[0];
    const float* Wc = (const float*)d_in[1];
    const float* Wp = (const float*)d_in[2];
    const float* Wa = (const float*)d_in[3];
    const float* ba = (const float*)d_in[4];
    float* out = (float*)d_out;

    dim3 grid(128 / TW, 128 / TH, 2);   // (16, 64, 2)
    caps_fused<<<grid, 256, 0, stream>>>(x, Wc, Wp, Wa, ba, out);
}